// Round 1
// baseline (937.229 us; speedup 1.0000x reference)
//
#include <hip/hip_runtime.h>
#include <math.h>

// ---------- config ----------
#define T_TOK 4096
#define DIM   2048
#define NEXP  32
#define TOPK  4
#define CAP   160          // ceil(1.25*4096/32)
#define ECAP  (NEXP*CAP)   // 5120
#define ISZ   1024         // moe intermediate
#define ISH   2048         // shared intermediate (I*NSH)

typedef short bf16x8 __attribute__((ext_vector_type(8)));
typedef float f32x4  __attribute__((ext_vector_type(4)));

__device__ __forceinline__ unsigned int f2bf(float f){
  union { float f; unsigned int u; } v; v.f = f;
  return (v.u + 0x7fffu + ((v.u >> 16) & 1u)) >> 16;   // RNE
}
__device__ __forceinline__ float bf2f(unsigned int u){
  union { unsigned int u; float f; } v; v.u = u << 16; return v.f;
}

// ---------- fp32 -> bf16 convert ----------
__global__ __launch_bounds__(256) void cvt_k(const float* __restrict__ in,
                                             unsigned short* __restrict__ out, int n8){
  int i = blockIdx.x*256 + threadIdx.x;
  if (i >= n8) return;
  const float4 a = *(const float4*)&in[(size_t)i*8];
  const float4 b = *(const float4*)&in[(size_t)i*8 + 4];
  uint4 v;
  v.x = f2bf(a.x) | (f2bf(a.y) << 16);
  v.y = f2bf(a.z) | (f2bf(a.w) << 16);
  v.z = f2bf(b.x) | (f2bf(b.y) << 16);
  v.w = f2bf(b.z) | (f2bf(b.w) << 16);
  *(uint4*)&out[(size_t)i*8] = v;
}

// ---------- silu(g)*u elementwise (bf16 in/out) ----------
__global__ __launch_bounds__(256) void silu_k(const unsigned short* __restrict__ g,
                                              const unsigned short* __restrict__ u,
                                              unsigned short* __restrict__ h, int n8){
  int i = blockIdx.x*256 + threadIdx.x;
  if (i >= n8) return;
  uint4 gv = *(const uint4*)&g[(size_t)i*8];
  uint4 uv = *(const uint4*)&u[(size_t)i*8];
  uint4 o;
  #define SPAIR(gp, up) ({ \
    float g0 = bf2f((gp) & 0xffffu), g1 = bf2f((gp) >> 16); \
    float u0 = bf2f((up) & 0xffffu), u1 = bf2f((up) >> 16); \
    float h0 = g0 / (1.f + __expf(-g0)) * u0; \
    float h1 = g1 / (1.f + __expf(-g1)) * u1; \
    f2bf(h0) | (f2bf(h1) << 16); })
  o.x = SPAIR(gv.x, uv.x);
  o.y = SPAIR(gv.y, uv.y);
  o.z = SPAIR(gv.z, uv.z);
  o.w = SPAIR(gv.w, uv.w);
  #undef SPAIR
  *(uint4*)&h[(size_t)i*8] = o;
}

// ---------- router: fp64 logits, exact top-k semantics ----------
// 4 tokens per block, 256 threads (4 waves x 8 experts each)
__global__ __launch_bounds__(256) void router_k(const float* __restrict__ x,
                                                const float* __restrict__ rw,
                                                const float* __restrict__ eb,
                                                int* __restrict__ tki,
                                                float* __restrict__ tkw){
  __shared__ float  xs[4][DIM];
  __shared__ double ssh[4][NEXP];
  const int tb = blockIdx.x * 4;
  const int tid = threadIdx.x;
  for (int i = tid; i < 4*(DIM/4); i += 256){
    int t = i >> 9, c = (i & 511) << 2;
    *(float4*)&xs[t][c] = *(const float4*)&x[(size_t)(tb + t)*DIM + c];
  }
  __syncthreads();
  const int lane = tid & 63, wv = tid >> 6;
  for (int ei = 0; ei < 8; ++ei){
    int e = wv*8 + ei;
    double a0=0, a1=0, a2=0, a3=0;
    for (int d = lane; d < DIM; d += 64){
      double w = (double)rw[(size_t)e*DIM + d];
      a0 += (double)xs[0][d] * w;
      a1 += (double)xs[1][d] * w;
      a2 += (double)xs[2][d] * w;
      a3 += (double)xs[3][d] * w;
    }
    for (int off = 32; off; off >>= 1){
      a0 += __shfl_down(a0, off);
      a1 += __shfl_down(a1, off);
      a2 += __shfl_down(a2, off);
      a3 += __shfl_down(a3, off);
    }
    if (lane == 0){ ssh[0][e]=a0; ssh[1][e]=a1; ssh[2][e]=a2; ssh[3][e]=a3; }
  }
  __syncthreads();
  if (tid < 4){
    const int t = tid;
    double s[NEXP], sc[NEXP];
    for (int e = 0; e < NEXP; ++e){
      double sig = 1.0 / (1.0 + exp(-ssh[t][e]));
      s[e] = sig; sc[e] = sig + (double)eb[e];
    }
    // group scores: sum of top-2 within each group of 4
    double gsc[8];
    for (int g = 0; g < 8; ++g){
      double b0=sc[g*4],b1=sc[g*4+1],b2=sc[g*4+2],b3=sc[g*4+3];
      double h1=fmax(b0,b1), l1=fmin(b0,b1);
      double h2=fmax(b2,b3), l2=fmin(b2,b3);
      double top = fmax(h1,h2);
      double sec = fmax(fmin(h1,h2), (h1 >= h2) ? l1 : l2);
      gsc[g] = top + sec;
    }
    // top-3 groups (strict >, ties -> lower index, matches lax.top_k)
    int gsel = 0;
    for (int r = 0; r < 3; ++r){
      int bi = -1; double bv = -1e300;
      for (int g = 0; g < 8; ++g)
        if (!((gsel >> g) & 1) && gsc[g] > bv){ bv = gsc[g]; bi = g; }
      gsel |= 1 << bi;
    }
    // masked top-4 experts
    double mval[NEXP];
    for (int e = 0; e < NEXP; ++e)
      mval[e] = ((gsel >> (e >> 2)) & 1) ? sc[e] : 0.0;
    int idx4[4]; double wsum = 0.0, wv4[4];
    for (int r = 0; r < 4; ++r){
      int bi = -1; double bv = -1e300;
      for (int e = 0; e < NEXP; ++e)
        if (mval[e] > bv){ bv = mval[e]; bi = e; }
      idx4[r] = bi; mval[bi] = -1e300;
      wv4[r] = s[bi]; wsum += wv4[r];
    }
    const int gt = tb + t;
    for (int r = 0; r < 4; ++r){
      tki[gt*4 + r] = idx4[r];
      tkw[gt*4 + r] = (float)(wv4[r] / (wsum + 1e-20) * 2.5);
    }
  }
}

// ---------- dispatch: wave per expert, stable-order rank scan ----------
__global__ __launch_bounds__(1024) void dispatch_k(const int* __restrict__ tki,
                                                   const float* __restrict__ tkw,
                                                   int* __restrict__ stok,
                                                   float* __restrict__ sw){
  const int e = blockIdx.x*16 + (threadIdx.x >> 6);
  const int lane = threadIdx.x & 63;
  int base = 0;
  for (int it = 0; it < (T_TOK*TOPK)/64; ++it){
    if (base >= CAP) break;
    int idx = it*64 + lane;
    int ex = tki[idx];
    bool m = (ex == e);
    unsigned long long mk = __ballot(m);
    int pos = base + __popcll(mk & ((1ull << lane) - 1ull));
    if (m && pos < CAP){
      stok[e*CAP + pos] = idx >> 2;       // token = flat/K
      sw[e*CAP + pos]   = tkw[idx];
    }
    base += __popcll(mk);
  }
}

// ---------- unified MFMA GEMM ----------
// MODE 0: C(bf16)=A(bf16)@B^T(f32 [N,K])          (shared gate/up)
// MODE 1: out(f32 plain)=A(bf16)@B^T(f32 [N,K])   (shared down)
// MODE 2: C(bf16)=gather(A)@B(f32 [K,N])          (expert gate/up), A rows via slots_token
// MODE 3: out(f32 atomic,scaled)=A@B(f32 [K,N])   (expert down)
template<int MODE>
__global__ __launch_bounds__(256)
void gemm_k(const unsigned short* __restrict__ Ab, const float* __restrict__ Bb,
            void* __restrict__ Co, const int* __restrict__ stok,
            const float* __restrict__ sw,
            int M, int N, int K, int lda, int ldb, int ldc){
  constexpr int FM = (MODE <= 1) ? 4 : 5;   // M-frags per wave
  constexpr int BM = FM * 32;               // 128 or 160
  constexpr int BK = 32;
  constexpr int ACH = BM * 4;               // 16B chunks in A tile
  constexpr int AIT = (ACH + 255) / 256;

  __shared__ uint4 AldsV[BM*BK/8];
  __shared__ uint4 BldsV[128*BK/8];
  unsigned short* Alds = (unsigned short*)AldsV;
  unsigned short* Blds = (unsigned short*)BldsV;

  const int tid = threadIdx.x;
  const int e  = blockIdx.z;
  const int nb = blockIdx.x * 128;
  const int mb = blockIdx.y * BM;

  const float* B = Bb + (size_t)e * (size_t)K * (size_t)ldb;

  int arow[AIT];
  #pragma unroll
  for (int it = 0; it < AIT; ++it){
    int chunk = tid + it*256;
    int row = chunk >> 2;
    if (chunk < ACH){
      if constexpr (MODE == 2)      arow[it] = stok[e*CAP + row];
      else if constexpr (MODE == 3) arow[it] = e*CAP + row;
      else                          arow[it] = (mb + row < M) ? (mb + row) : -1;
    } else arow[it] = -2;
  }

  const int lane = tid & 63;
  const int wid  = tid >> 6;
  const int wm = (wid >> 1) * (FM*16);
  const int wn = (wid & 1) * 64;
  const int r16 = lane & 15;
  const int ko8 = (lane >> 4) * 8;

  f32x4 acc[FM][4];
  #pragma unroll
  for (int i = 0; i < FM; ++i)
    #pragma unroll
    for (int j = 0; j < 4; ++j) acc[i][j] = f32x4{0.f,0.f,0.f,0.f};

  const int kiters = K / BK;
  for (int kt = 0; kt < kiters; ++kt){
    const int k0 = kt * BK;
    __syncthreads();
    // ---- A stage (bf16 source, optional gather) ----
    #pragma unroll
    for (int it = 0; it < AIT; ++it){
      int chunk = tid + it*256;
      if (chunk < ACH){
        int row = chunk >> 2, ko = chunk & 3;
        uint4 v = uint4{0u,0u,0u,0u};
        int r = arow[it];
        if (r >= 0) v = *(const uint4*)&Ab[(size_t)r*lda + k0 + ko*8];
        AldsV[row*4 + ko] = v;
      }
    }
    // ---- B stage ----
    if constexpr (MODE <= 1){
      // B^T form: [N,K] f32, K contiguous
      #pragma unroll
      for (int it = 0; it < 2; ++it){
        int chunk = tid + it*256;
        int n = chunk >> 2, ko = chunk & 3;
        const float* s = &B[(size_t)(nb + n)*ldb + k0 + ko*8];
        float4 f0 = *(const float4*)s;
        float4 f1 = *(const float4*)(s + 4);
        uint4 v;
        v.x = f2bf(f0.x) | (f2bf(f0.y) << 16);
        v.y = f2bf(f0.z) | (f2bf(f0.w) << 16);
        v.z = f2bf(f1.x) | (f2bf(f1.y) << 16);
        v.w = f2bf(f1.z) | (f2bf(f1.w) << 16);
        BldsV[n*4 + ko] = v;
      }
    } else {
      // [K,N] form: register transpose 8k x 2n
      const int ko = tid & 3, n2 = tid >> 2;
      const float* bp = &B[(size_t)(k0 + ko*8)*ldb + nb + n2*2];
      float2 wv[8];
      #pragma unroll
      for (int j = 0; j < 8; ++j) wv[j] = *(const float2*)(bp + (size_t)j*ldb);
      uint4 vlo, vhi;
      vlo.x = f2bf(wv[0].x) | (f2bf(wv[1].x) << 16);
      vlo.y = f2bf(wv[2].x) | (f2bf(wv[3].x) << 16);
      vlo.z = f2bf(wv[4].x) | (f2bf(wv[5].x) << 16);
      vlo.w = f2bf(wv[6].x) | (f2bf(wv[7].x) << 16);
      vhi.x = f2bf(wv[0].y) | (f2bf(wv[1].y) << 16);
      vhi.y = f2bf(wv[2].y) | (f2bf(wv[3].y) << 16);
      vhi.z = f2bf(wv[4].y) | (f2bf(wv[5].y) << 16);
      vhi.w = f2bf(wv[6].y) | (f2bf(wv[7].y) << 16);
      BldsV[(n2*2)*4 + ko]   = vlo;
      BldsV[(n2*2+1)*4 + ko] = vhi;
    }
    __syncthreads();
    // ---- MFMA ----
    bf16x8 af[FM], bfr[4];
    #pragma unroll
    for (int i = 0; i < FM; ++i)
      af[i] = *(const bf16x8*)&Alds[(wm + i*16 + r16)*BK + ko8];
    #pragma unroll
    for (int j = 0; j < 4; ++j)
      bfr[j] = *(const bf16x8*)&Blds[(wn + j*16 + r16)*BK + ko8];
    #pragma unroll
    for (int i = 0; i < FM; ++i)
      #pragma unroll
      for (int j = 0; j < 4; ++j)
        acc[i][j] = __builtin_amdgcn_mfma_f32_16x16x32_bf16(af[i], bfr[j], acc[i][j], 0, 0, 0);
  }

  // ---- epilogue ----
  const int coln = nb + wn + r16;
  #pragma unroll
  for (int i = 0; i < FM; ++i){
    int mloc = wm + i*16 + ((lane >> 4) << 2);
    #pragma unroll
    for (int r = 0; r < 4; ++r){
      int m = mloc + r;
      if constexpr (MODE == 0){
        int grow = mb + m;
        if (grow < M){
          unsigned short* C = (unsigned short*)Co;
          #pragma unroll
          for (int j = 0; j < 4; ++j)
            C[(size_t)grow*ldc + coln + j*16] = (unsigned short)f2bf(acc[i][j][r]);
        }
      } else if constexpr (MODE == 1){
        int grow = mb + m;
        if (grow < M){
          float* C = (float*)Co;
          #pragma unroll
          for (int j = 0; j < 4; ++j)
            C[(size_t)grow*ldc + coln + j*16] = acc[i][j][r];
        }
      } else if constexpr (MODE == 2){
        int slot = e*CAP + m;
        unsigned short* C = (unsigned short*)Co;
        #pragma unroll
        for (int j = 0; j < 4; ++j)
          C[(size_t)slot*ldc + coln + j*16] = (unsigned short)f2bf(acc[i][j][r]);
      } else {
        int slot = e*CAP + m;
        float w = sw[slot];
        if (w != 0.f){
          int tok = stok[slot];
          float* C = (float*)Co;
          #pragma unroll
          for (int j = 0; j < 4; ++j)
            atomicAdd(&C[(size_t)tok*ldc + coln + j*16], w * acc[i][j][r]);
        }
      }
    }
  }
}

extern "C" void kernel_launch(void* const* d_in, const int* in_sizes, int n_in,
                              void* d_out, int out_size, void* d_ws, size_t ws_size,
                              hipStream_t stream){
  const float* x  = (const float*)d_in[0];
  const float* rw = (const float*)d_in[1];
  const float* eb = (const float*)d_in[2];
  const float* wg = (const float*)d_in[3];
  const float* wu = (const float*)d_in[4];
  const float* wd = (const float*)d_in[5];
  const float* sg = (const float*)d_in[6];
  const float* su = (const float*)d_in[7];
  const float* sd = (const float*)d_in[8];
  float* out = (float*)d_out;

  char* ws = (char*)d_ws;
  unsigned short* xbf  = (unsigned short*)ws; ws += (size_t)T_TOK*DIM*2;
  unsigned short* gbuf = (unsigned short*)ws; ws += (size_t)T_TOK*ISH*2;
  unsigned short* ubuf = (unsigned short*)ws; ws += (size_t)T_TOK*ISH*2;
  unsigned short* hbuf = (unsigned short*)ws; ws += (size_t)T_TOK*ISH*2;
  int*   tki  = (int*)ws;   ws += (size_t)T_TOK*TOPK*4;
  float* tkw  = (float*)ws; ws += (size_t)T_TOK*TOPK*4;
  int*   stok = (int*)ws;   ws += (size_t)ECAP*4;
  float* sw   = (float*)ws; ws += (size_t)ECAP*4;

  // x -> bf16
  cvt_k<<<(T_TOK*DIM/8)/256, 256, 0, stream>>>(x, xbf, T_TOK*DIM/8);
  // router + dispatch
  router_k<<<T_TOK/4, 256, 0, stream>>>(x, rw, eb, tki, tkw);
  hipMemsetAsync(stok, 0, (size_t)ECAP*8, stream);   // stok + sw (contiguous)
  dispatch_k<<<2, 1024, 0, stream>>>(tki, tkw, stok, sw);

  // shared MLP: g,u -> h -> out (plain store initializes d_out)
  gemm_k<0><<<dim3(16,32,1), 256, 0, stream>>>(xbf, sg, gbuf, nullptr, nullptr,
                                               T_TOK, ISH, DIM, DIM, DIM, ISH);
  gemm_k<0><<<dim3(16,32,1), 256, 0, stream>>>(xbf, su, ubuf, nullptr, nullptr,
                                               T_TOK, ISH, DIM, DIM, DIM, ISH);
  silu_k<<<(T_TOK*ISH/8)/256, 256, 0, stream>>>(gbuf, ubuf, hbuf, T_TOK*ISH/8);
  gemm_k<1><<<dim3(16,32,1), 256, 0, stream>>>(hbuf, sd, out, nullptr, nullptr,
                                               T_TOK, DIM, ISH, ISH, ISH, DIM);

  // routed experts (reuse g/u/h buffers): gate, up -> h -> down (atomic scatter)
  gemm_k<2><<<dim3(8,1,NEXP), 256, 0, stream>>>(xbf, wg, gbuf, stok, sw,
                                                CAP, ISZ, DIM, DIM, ISZ, ISZ);
  gemm_k<2><<<dim3(8,1,NEXP), 256, 0, stream>>>(xbf, wu, ubuf, stok, sw,
                                                CAP, ISZ, DIM, DIM, ISZ, ISZ);
  silu_k<<<(ECAP*ISZ/8)/256, 256, 0, stream>>>(gbuf, ubuf, hbuf, ECAP*ISZ/8);
  gemm_k<3><<<dim3(16,1,NEXP), 256, 0, stream>>>(hbuf, wd, out, stok, sw,
                                                 CAP, DIM, ISZ, ISZ, DIM, DIM);
}

// Round 2
// 735.275 us; speedup vs baseline: 1.2747x; 1.2747x over previous
//
#include <hip/hip_runtime.h>
#include <math.h>

// ---------- config ----------
#define T_TOK 4096
#define DIM   2048
#define NEXP  32
#define TOPK  4
#define CAP   160          // ceil(1.25*4096/32)
#define ECAP  (NEXP*CAP)   // 5120
#define ISZ   1024         // moe intermediate
#define ISH   2048         // shared intermediate (I*NSH)

typedef short bf16x8 __attribute__((ext_vector_type(8)));
typedef float f32x4  __attribute__((ext_vector_type(4)));

__device__ __forceinline__ unsigned int f2bf(float f){
  union { float f; unsigned int u; } v; v.f = f;
  return (v.u + 0x7fffu + ((v.u >> 16) & 1u)) >> 16;   // RNE
}
__device__ __forceinline__ float bf2f(unsigned int u){
  union { unsigned int u; float f; } v; v.u = u << 16; return v.f;
}

// async global->LDS, 16B per lane; LDS base wave-uniform, global addr per-lane
#define GLOAD16(g, l) __builtin_amdgcn_global_load_lds( \
    (const __attribute__((address_space(1))) unsigned int*)(g), \
    (__attribute__((address_space(3))) unsigned int*)(l), 16, 0, 0)

// ---------- fp32 -> bf16 convert ----------
__global__ __launch_bounds__(256) void cvt_k(const float* __restrict__ in,
                                             unsigned short* __restrict__ out, int n8){
  int i = blockIdx.x*256 + threadIdx.x;
  if (i >= n8) return;
  const float4 a = *(const float4*)&in[(size_t)i*8];
  const float4 b = *(const float4*)&in[(size_t)i*8 + 4];
  uint4 v;
  v.x = f2bf(a.x) | (f2bf(a.y) << 16);
  v.y = f2bf(a.z) | (f2bf(a.w) << 16);
  v.z = f2bf(b.x) | (f2bf(b.y) << 16);
  v.w = f2bf(b.z) | (f2bf(b.w) << 16);
  *(uint4*)&out[(size_t)i*8] = v;
}

// ---------- router: fp64 logits, exact top-k semantics ----------
__global__ __launch_bounds__(256) void router_k(const float* __restrict__ x,
                                                const float* __restrict__ rw,
                                                const float* __restrict__ eb,
                                                int* __restrict__ tki,
                                                float* __restrict__ tkw){
  __shared__ float  xs[4][DIM];
  __shared__ double ssh[4][NEXP];
  const int tb = blockIdx.x * 4;
  const int tid = threadIdx.x;
  for (int i = tid; i < 4*(DIM/4); i += 256){
    int t = i >> 9, c = (i & 511) << 2;
    *(float4*)&xs[t][c] = *(const float4*)&x[(size_t)(tb + t)*DIM + c];
  }
  __syncthreads();
  const int lane = tid & 63, wv = tid >> 6;
  for (int ei = 0; ei < 8; ++ei){
    int e = wv*8 + ei;
    double a0=0, a1=0, a2=0, a3=0;
    for (int d = lane; d < DIM; d += 64){
      double w = (double)rw[(size_t)e*DIM + d];
      a0 += (double)xs[0][d] * w;
      a1 += (double)xs[1][d] * w;
      a2 += (double)xs[2][d] * w;
      a3 += (double)xs[3][d] * w;
    }
    for (int off = 32; off; off >>= 1){
      a0 += __shfl_down(a0, off);
      a1 += __shfl_down(a1, off);
      a2 += __shfl_down(a2, off);
      a3 += __shfl_down(a3, off);
    }
    if (lane == 0){ ssh[0][e]=a0; ssh[1][e]=a1; ssh[2][e]=a2; ssh[3][e]=a3; }
  }
  __syncthreads();
  if (tid < 4){
    const int t = tid;
    double s[NEXP], sc[NEXP];
    for (int e = 0; e < NEXP; ++e){
      double sig = 1.0 / (1.0 + exp(-ssh[t][e]));
      s[e] = sig; sc[e] = sig + (double)eb[e];
    }
    double gsc[8];
    for (int g = 0; g < 8; ++g){
      double b0=sc[g*4],b1=sc[g*4+1],b2=sc[g*4+2],b3=sc[g*4+3];
      double h1=fmax(b0,b1), l1=fmin(b0,b1);
      double h2=fmax(b2,b3), l2=fmin(b2,b3);
      double top = fmax(h1,h2);
      double sec = fmax(fmin(h1,h2), (h1 >= h2) ? l1 : l2);
      gsc[g] = top + sec;
    }
    int gsel = 0;
    for (int r = 0; r < 3; ++r){
      int bi = -1; double bv = -1e300;
      for (int g = 0; g < 8; ++g)
        if (!((gsel >> g) & 1) && gsc[g] > bv){ bv = gsc[g]; bi = g; }
      gsel |= 1 << bi;
    }
    double mval[NEXP];
    for (int e = 0; e < NEXP; ++e)
      mval[e] = ((gsel >> (e >> 2)) & 1) ? sc[e] : 0.0;
    int idx4[4]; double wsum = 0.0, wv4[4];
    for (int r = 0; r < 4; ++r){
      int bi = -1; double bv = -1e300;
      for (int e = 0; e < NEXP; ++e)
        if (mval[e] > bv){ bv = mval[e]; bi = e; }
      idx4[r] = bi; mval[bi] = -1e300;
      wv4[r] = s[bi]; wsum += wv4[r];
    }
    const int gt = tb + t;
    for (int r = 0; r < 4; ++r){
      tki[gt*4 + r] = idx4[r];
      tkw[gt*4 + r] = (float)(wv4[r] / (wsum + 1e-20) * 2.5);
    }
  }
}

// ---------- dispatch: wave per expert, stable-order rank scan ----------
__global__ __launch_bounds__(1024) void dispatch_k(const int* __restrict__ tki,
                                                   const float* __restrict__ tkw,
                                                   int* __restrict__ stok,
                                                   float* __restrict__ sw){
  const int e = blockIdx.x*16 + (threadIdx.x >> 6);
  const int lane = threadIdx.x & 63;
  int base = 0;
  for (int it = 0; it < (T_TOK*TOPK)/64; ++it){
    if (base >= CAP) break;
    int idx = it*64 + lane;
    int ex = tki[idx];
    bool m = (ex == e);
    unsigned long long mk = __ballot(m);
    int pos = base + __popcll(mk & ((1ull << lane) - 1ull));
    if (m && pos < CAP){
      stok[e*CAP + pos] = idx >> 2;
      sw[e*CAP + pos]   = tkw[idx];
    }
    base += __popcll(mk);
  }
}

// ---------- unified double-buffered MFMA GEMM ----------
// GU=1: H(bf16) = silu(A@Bg) * (A@Bu)   (fused gate+up+silu)
// GU=0, EXPERT=0: out(f32 plain) = A@B  (shared down)
// GU=0, EXPERT=1: out(f32 atomic, scaled scatter) = A@B (expert down)
// EXPERT: A rows gathered (GU) or slot rows; B layout [K,N]; else B^T layout [N,K].
template<int EXPERT, int GU>
__global__ __launch_bounds__(256)
void gemm2_k(const unsigned short* __restrict__ Ab,
             const float* __restrict__ B0, const float* __restrict__ B1,
             void* __restrict__ Co,
             const int* __restrict__ stok, const float* __restrict__ sw){
  constexpr int BM  = EXPERT ? 160 : 128;
  constexpr int FM  = BM / 32;
  constexpr int KK  = GU ? DIM : (EXPERT ? ISZ : ISH);
  constexpr int LDA = GU ? DIM : (EXPERT ? ISZ : ISH);
  constexpr int LDB = EXPERT ? (GU ? ISZ : DIM) : (GU ? DIM : ISH);
  constexpr int LDC = GU ? (EXPERT ? ISZ : ISH) : DIM;
  constexpr int NBW = GU ? 64 : 128;      // output cols per block (per matrix for GU)
  constexpr int ACH = BM*4;               // 16B chunks in A tile
  constexpr int AIT = (ACH + 255)/256;
  constexpr int NT  = KK/32;

  __shared__ uint4 AldsV[2][BM*4];
  __shared__ uint4 BldsV[2][128*4];

  const int tid  = threadIdx.x;
  const int lane = tid & 63, wid = tid >> 6;
  const int e    = EXPERT ? blockIdx.z : 0;
  const int nb   = (EXPERT ? blockIdx.x : blockIdx.y) * NBW;
  const int mb   = EXPERT ? e*CAP : blockIdx.x * BM;

  // ---- A gather pointers (per-lane), wave-chunked for global_load_lds ----
  const unsigned short* aptr[AIT];
  #pragma unroll
  for (int it = 0; it < AIT; ++it){
    int c = tid + it*256;
    int row = (c < ACH) ? (c >> 2) : 0;
    int ar;
    if constexpr (EXPERT && GU) ar = stok[mb + row];
    else                        ar = mb + row;
    aptr[it] = Ab + (size_t)ar*LDA + (c & 3)*8;
  }

  auto stageA = [&](int k0, int buf){
    #pragma unroll
    for (int it = 0; it < AIT; ++it){
      if ((it+1)*256 <= ACH || tid < (ACH & 255)){   // tail guard is wave-uniform (128 = 2 waves)
        GLOAD16(aptr[it] + k0, (char*)AldsV[buf] + (size_t)(it*256 + wid*64)*16);
      }
    }
  };

  // ---- B staging setup ----
  const float* bsrow = nullptr; int bv = 0, bkh = 0;       // shared (B^T) path
  const float* becol = nullptr; int bev0 = 0, beko = 0;    // expert ([K,N]) path
  if constexpr (!EXPERT){
    bv = tid >> 1; bkh = tid & 1;
    const float* src; int row;
    if constexpr (GU){ int mat = bv >> 6; src = mat ? B1 : B0; row = nb + (bv & 63); }
    else             { src = B0; row = nb + bv; }
    bsrow = src + (size_t)row*LDB + bkh*16;
  } else {
    if constexpr (GU){
      int mat = tid >> 7, r = tid & 127;
      const float* src = (mat ? B1 : B0) + (size_t)e*KK*LDB;
      beko = r & 3; int n2 = r >> 2; bev0 = mat*64 + n2*2;
      becol = src + (size_t)beko*8*LDB + nb + n2*2;
    } else {
      const float* src = B0 + (size_t)e*KK*LDB;
      beko = tid & 3; int n2 = tid >> 2; bev0 = n2*2;
      becol = src + (size_t)beko*8*LDB + nb + n2*2;
    }
  }

  float4 bq[4]; float2 bp2[8];
  auto loadB = [&](int k0){
    if constexpr (!EXPERT){
      const float* p = bsrow + k0;
      #pragma unroll
      for (int q = 0; q < 4; ++q) bq[q] = *(const float4*)(p + q*4);
    } else {
      const float* p = becol + (size_t)k0*LDB;
      #pragma unroll
      for (int j = 0; j < 8; ++j) bp2[j] = *(const float2*)(p + (size_t)j*LDB);
    }
  };
  auto writeB = [&](int buf){
    unsigned short* Bl = (unsigned short*)BldsV[buf];
    if constexpr (!EXPERT){
      uint4 w0, w1;
      w0.x = f2bf(bq[0].x)|(f2bf(bq[0].y)<<16); w0.y = f2bf(bq[0].z)|(f2bf(bq[0].w)<<16);
      w0.z = f2bf(bq[1].x)|(f2bf(bq[1].y)<<16); w0.w = f2bf(bq[1].z)|(f2bf(bq[1].w)<<16);
      w1.x = f2bf(bq[2].x)|(f2bf(bq[2].y)<<16); w1.y = f2bf(bq[2].z)|(f2bf(bq[2].w)<<16);
      w1.z = f2bf(bq[3].x)|(f2bf(bq[3].y)<<16); w1.w = f2bf(bq[3].z)|(f2bf(bq[3].w)<<16);
      *(uint4*)&Bl[bv*32 + bkh*16]     = w0;
      *(uint4*)&Bl[bv*32 + bkh*16 + 8] = w1;
    } else {
      uint4 vlo, vhi;
      vlo.x = f2bf(bp2[0].x)|(f2bf(bp2[1].x)<<16);
      vlo.y = f2bf(bp2[2].x)|(f2bf(bp2[3].x)<<16);
      vlo.z = f2bf(bp2[4].x)|(f2bf(bp2[5].x)<<16);
      vlo.w = f2bf(bp2[6].x)|(f2bf(bp2[7].x)<<16);
      vhi.x = f2bf(bp2[0].y)|(f2bf(bp2[1].y)<<16);
      vhi.y = f2bf(bp2[2].y)|(f2bf(bp2[3].y)<<16);
      vhi.z = f2bf(bp2[4].y)|(f2bf(bp2[5].y)<<16);
      vhi.w = f2bf(bp2[6].y)|(f2bf(bp2[7].y)<<16);
      *(uint4*)&Bl[(bev0    )*32 + beko*8] = vlo;
      *(uint4*)&Bl[(bev0 + 1)*32 + beko*8] = vhi;
    }
  };

  const int wm  = (wid >> 1) * (FM*16);
  const int wn  = wid & 1;
  const int r16 = lane & 15, ko8 = (lane >> 4)*8;

  f32x4 acc[FM][4];
  #pragma unroll
  for (int i = 0; i < FM; ++i)
    #pragma unroll
    for (int j = 0; j < 4; ++j) acc[i][j] = f32x4{0.f,0.f,0.f,0.f};

  // prologue: fill buffer 0
  stageA(0, 0);
  loadB(0);
  writeB(0);
  __syncthreads();

  #pragma unroll 2
  for (int t = 0; t < NT; ++t){
    const int cur = t & 1;
    const bool pf = (t + 1 < NT);
    if (pf){ stageA((t+1)*32, cur^1); loadB((t+1)*32); }   // prefetch in flight over MFMA
    const unsigned short* Al = (const unsigned short*)AldsV[cur];
    const unsigned short* Bl = (const unsigned short*)BldsV[cur];
    bf16x8 af[FM], bfr[4];
    #pragma unroll
    for (int i = 0; i < FM; ++i)
      af[i] = *(const bf16x8*)&Al[(wm + i*16 + r16)*32 + ko8];
    #pragma unroll
    for (int j = 0; j < 4; ++j){
      int row = GU ? ((j >> 1)*64 + wn*32 + (j & 1)*16) : (wn*64 + j*16);
      bfr[j] = *(const bf16x8*)&Bl[(row + r16)*32 + ko8];
    }
    #pragma unroll
    for (int i = 0; i < FM; ++i)
      #pragma unroll
      for (int j = 0; j < 4; ++j)
        acc[i][j] = __builtin_amdgcn_mfma_f32_16x16x32_bf16(af[i], bfr[j], acc[i][j], 0, 0, 0);
    if (pf) writeB(cur^1);
    __syncthreads();
  }

  // ---- epilogue ----
  #pragma unroll
  for (int i = 0; i < FM; ++i){
    const int m0 = wm + i*16 + ((lane >> 4) << 2);
    #pragma unroll
    for (int r = 0; r < 4; ++r){
      const int m = m0 + r;
      if constexpr (GU){
        unsigned short* H = (unsigned short*)Co;
        const int orow = mb + m;
        #pragma unroll
        for (int jj = 0; jj < 2; ++jj){
          float g = acc[i][jj][r], u = acc[i][2+jj][r];
          float h = g / (1.f + __expf(-g)) * u;
          int col = nb + wn*32 + jj*16 + r16;
          H[(size_t)orow*LDC + col] = (unsigned short)f2bf(h);
        }
      } else if constexpr (EXPERT){
        const int slot = mb + m;
        float w = sw[slot];
        if (w != 0.f){
          int tok = stok[slot];
          float* O = (float*)Co;
          #pragma unroll
          for (int j = 0; j < 4; ++j){
            int col = nb + wn*64 + j*16 + r16;
            atomicAdd(&O[(size_t)tok*LDC + col], w * acc[i][j][r]);
          }
        }
      } else {
        float* O = (float*)Co;
        const int orow = mb + m;
        #pragma unroll
        for (int j = 0; j < 4; ++j){
          int col = nb + wn*64 + j*16 + r16;
          O[(size_t)orow*LDC + col] = acc[i][j][r];
        }
      }
    }
  }
}

extern "C" void kernel_launch(void* const* d_in, const int* in_sizes, int n_in,
                              void* d_out, int out_size, void* d_ws, size_t ws_size,
                              hipStream_t stream){
  const float* x  = (const float*)d_in[0];
  const float* rw = (const float*)d_in[1];
  const float* eb = (const float*)d_in[2];
  const float* wg = (const float*)d_in[3];
  const float* wu = (const float*)d_in[4];
  const float* wd = (const float*)d_in[5];
  const float* sg = (const float*)d_in[6];
  const float* su = (const float*)d_in[7];
  const float* sd = (const float*)d_in[8];
  float* out = (float*)d_out;

  char* ws = (char*)d_ws;
  unsigned short* xbf = (unsigned short*)ws; ws += (size_t)T_TOK*DIM*2;
  unsigned short* hsh = (unsigned short*)ws; ws += (size_t)T_TOK*ISH*2;   // shared silu(g)*u
  unsigned short* hex = (unsigned short*)ws; ws += (size_t)ECAP*ISZ*2;    // expert silu(g)*u
  int*   tki  = (int*)ws;   ws += (size_t)T_TOK*TOPK*4;
  float* tkw  = (float*)ws; ws += (size_t)T_TOK*TOPK*4;
  int*   stok = (int*)ws;   ws += (size_t)ECAP*4;
  float* sw   = (float*)ws; ws += (size_t)ECAP*4;

  // x -> bf16; router; dispatch
  cvt_k<<<(T_TOK*DIM/8)/256, 256, 0, stream>>>(x, xbf, T_TOK*DIM/8);
  router_k<<<T_TOK/4, 256, 0, stream>>>(x, rw, eb, tki, tkw);
  hipMemsetAsync(stok, 0, (size_t)ECAP*8, stream);   // stok + sw contiguous
  dispatch_k<<<2, 1024, 0, stream>>>(tki, tkw, stok, sw);

  // shared MLP: fused gate+up+silu -> h ; down -> out (plain store initializes d_out)
  gemm2_k<0,1><<<dim3(T_TOK/128, ISH/64), 256, 0, stream>>>(xbf, sg, su, hsh, nullptr, nullptr);
  gemm2_k<0,0><<<dim3(T_TOK/128, DIM/128), 256, 0, stream>>>(hsh, sd, nullptr, out, nullptr, nullptr);

  // routed experts: fused gate+up+silu -> h ; down -> atomic scaled scatter into out
  gemm2_k<1,1><<<dim3(ISZ/64, 1, NEXP), 256, 0, stream>>>(xbf, wg, wu, hex, stok, sw);
  gemm2_k<1,0><<<dim3(DIM/128, 1, NEXP), 256, 0, stream>>>(hex, wd, nullptr, out, stok, sw);
}